// Round 7
// baseline (364.437 us; speedup 1.0000x reference)
//
#include <hip/hip_runtime.h>
#include <hip/hip_bf16.h>

#define Nn 50000
#define Ee 600000
#define Dd 128
#define EPSc 1e-5f

typedef unsigned int u32;
typedef unsigned short u16;
typedef short s16x8 __attribute__((ext_vector_type(8)));
typedef float f32x4 __attribute__((ext_vector_type(4)));

__device__ inline float bf2f(u32 lo16) { return __uint_as_float(lo16 << 16); }
__device__ inline u16 f2bf(float f) {
    u32 b = __float_as_uint(f);
    return (u16)((b + 0x7fffu + ((b >> 16) & 1u)) >> 16);  // RTN-even
}
__device__ inline void gload16(const void* g, void* l) {
    __builtin_amdgcn_global_load_lds(
        (const __attribute__((address_space(1))) u32*)g,
        (__attribute__((address_space(3))) u32*)l, 16, 0, 0);
}

// ---------------- CSR build ----------------
__global__ __launch_bounds__(256) void hist_k(const int* __restrict__ dst,
                                              int* __restrict__ cnt) {
    int e = blockIdx.x * 256 + threadIdx.x;
    if (e < Ee) atomicAdd(&cnt[dst[e]], 1);
}

__global__ __launch_bounds__(1024) void scan_k(const int* __restrict__ cnt,
                                               int* __restrict__ rowp) {
    __shared__ int wsum[16];
    __shared__ int carry_s;
    const int t = threadIdx.x, lane = t & 63, w = t >> 6;
    if (t == 0) { carry_s = 0; rowp[0] = 0; }
    __syncthreads();
    for (int base = 0; base < Nn; base += 1024) {
        int v = (base + t < Nn) ? cnt[base + t] : 0;
        int incl = v;
#pragma unroll
        for (int off = 1; off < 64; off <<= 1) {
            int u = __shfl_up(incl, off, 64);
            if (lane >= off) incl += u;
        }
        if (lane == 63) wsum[w] = incl;
        __syncthreads();
        if (t == 0) {
            int run = carry_s;
#pragma unroll
            for (int i = 0; i < 16; i++) { int s = wsum[i]; wsum[i] = run; run += s; }
            carry_s = run;
        }
        __syncthreads();
        if (base + t < Nn) rowp[base + t + 1] = wsum[w] + incl;
        __syncthreads();
    }
}

__global__ __launch_bounds__(256) void scatter_k(const int* __restrict__ src,
                                                 const int* __restrict__ dst,
                                                 const int* __restrict__ et,
                                                 int* __restrict__ cursor,
                                                 int2* __restrict__ se) {
    int e = blockIdx.x * 256 + threadIdx.x;
    if (e < Ee) {
        int pos = atomicAdd(&cursor[dst[e]], 1);
        se[pos] = make_int2(src[e], et[e]);
    }
}

// ---------------- fp32 -> bf16 convert ----------------
__global__ __launch_bounds__(256) void conv_k(const float* __restrict__ in,
                                              u16* __restrict__ out) {
    const int total = Nn * 32;
    for (int i = blockIdx.x * 256 + threadIdx.x; i < total; i += gridDim.x * 256) {
        float4 v = ((const float4*)in)[i];
        ((ushort4*)out)[i] = make_ushort4(f2bf(v.x), f2bf(v.y), f2bf(v.z), f2bf(v.w));
    }
}

// ---------------- weight prep: Wt[c][k] = W[k][c] in bf16, k: V(512)|loop(128)
__global__ __launch_bounds__(256) void wprep_k(const float* __restrict__ V,
                                               const float* __restrict__ loop,
                                               u16* __restrict__ Wt) {
    int i = blockIdx.x * 256 + threadIdx.x;  // 128*640
    if (i >= 128 * 640) return;
    int c = i / 640, k = i - c * 640;
    float v = (k < 512) ? V[(size_t)k * 128 + c] : loop[(size_t)(k - 512) * 128 + c];
    Wt[i] = f2bf(v);
}

// ---------------- aggregation: yb16[n,b,:] = sum_e comb[et,b]*x16[src] -------
// 4-deep MLP: 4 independent clamped se loads -> 4 independent x-row gathers
// in flight per wave; tail edges zero-masked on the gathered value.
__global__ __launch_bounds__(256) void agg_k(const u16* __restrict__ x16,
                                             const int2* __restrict__ se,
                                             const int* __restrict__ rowp,
                                             const float* __restrict__ comb,
                                             u16* __restrict__ yb16) {
    const int node = blockIdx.x * 4 + (threadIdx.x >> 6);
    const int lane = threadIdx.x & 63;
    const int beg = rowp[node], end = rowp[node + 1];
    float a0x = 0.f, a0y = 0.f, a1x = 0.f, a1y = 0.f;
    float a2x = 0.f, a2y = 0.f, a3x = 0.f, a3y = 0.f;
    const int eL = end - 1;
    const int co = lane * 2;

    for (int e0 = beg; e0 < end; e0 += 4) {
        const int m = end - e0;
        const int2 rc0 = se[e0];
        const int2 rc1 = se[min(e0 + 1, eL)];
        const int2 rc2 = se[min(e0 + 2, eL)];
        const int2 rc3 = se[min(e0 + 3, eL)];
        u32 x0 = *(const u32*)&x16[(size_t)rc0.x * 128 + co];
        u32 x1 = *(const u32*)&x16[(size_t)rc1.x * 128 + co];
        u32 x2 = *(const u32*)&x16[(size_t)rc2.x * 128 + co];
        u32 x3 = *(const u32*)&x16[(size_t)rc3.x * 128 + co];
        if (m < 4) x3 = 0;
        if (m < 3) x2 = 0;
        if (m < 2) x1 = 0;
        const float4 c0 = ((const float4*)comb)[rc0.y];
        const float4 c1 = ((const float4*)comb)[rc1.y];
        const float4 c2 = ((const float4*)comb)[rc2.y];
        const float4 c3 = ((const float4*)comb)[rc3.y];
#define ACC1(c, xv)                                        \
        {                                                  \
            const float fx = bf2f((xv) & 0xffffu);         \
            const float fy = bf2f((xv) >> 16);             \
            a0x += c.x * fx; a0y += c.x * fy;              \
            a1x += c.y * fx; a1y += c.y * fy;              \
            a2x += c.z * fx; a2y += c.z * fy;              \
            a3x += c.w * fx; a3y += c.w * fy;              \
        }
        ACC1(c0, x0)
        ACC1(c1, x1)
        ACC1(c2, x2)
        ACC1(c3, x3)
#undef ACC1
    }
    u32* yp = (u32*)(yb16 + (size_t)node * 512);
    yp[lane]       = (u32)f2bf(a0x) | ((u32)f2bf(a0y) << 16);
    yp[64 + lane]  = (u32)f2bf(a1x) | ((u32)f2bf(a1y) << 16);
    yp[128 + lane] = (u32)f2bf(a2x) | ((u32)f2bf(a2y) << 16);
    yp[192 + lane] = (u32)f2bf(a3x) | ((u32)f2bf(a3y) << 16);
}

// ---------------- MFMA GEMM: OUT = relu([yb16|x16] @ Wt^T + bias) ------------
// BM=64 x BN=128, 4 waves (2x2, wave tile 32x64), BK=32, double-buffered LDS
// (2x12KB), 2-phase schedule: issue next tile's global_load_lds BEFORE current
// tile's ds_read+MFMA; one __syncthreads (vmcnt drain) per K-step.
// Fused BN stats: butterfly + LDS cross-wave reduce -> 1 atomic set per block.
__global__ __launch_bounds__(256) void gemm_mfma_k(const u16* __restrict__ yb16,
                                                   const u16* __restrict__ x16,
                                                   const u16* __restrict__ Wt,
                                                   const float* __restrict__ bias,
                                                   float* __restrict__ OUT,
                                                   float* __restrict__ stats) {
    // per buffer: A 64 rows x 64B = 4KB | B 128 rows x 64B = 8KB
    __shared__ __align__(16) char LDS[24576];
    const int tid = threadIdx.x;
    const int lane = tid & 63, wid = tid >> 6;
    const int wr = wid >> 1, wc = wid & 1;
    const int bm = blockIdx.x * 64;

    f32x4 acc[2][4] = {};

    // staging: 12 chunks of 16 rows (1024B each); rows 0-63 = A, 64-191 = B(Wt).
    // wave stages chunks [3*wid, 3*wid+3). gload_lds: lane i -> base + i*16,
    // i.e. row 16c+(i>>2), slot i&3. Source pre-swizzled: elem off =
    // ((slot ^ ((row>>1)&3))*8  -> ds_read side applies same XOR.
    const u16* ybp[3];
    const u16* xp[3];
    const u16* wtp[3];
    int ldsoff[3];
#pragma unroll
    for (int j = 0; j < 3; j++) {
        const int c = wid * 3 + j;
        const int row = c * 16 + (lane >> 2);
        const int off = (((lane & 3) ^ ((row >> 1) & 3)) * 8);
        ldsoff[j] = c * 1024;
        if (row < 64) {
            int ga = bm + row;
            if (ga >= Nn) ga = Nn - 1;
            ybp[j] = yb16 + (size_t)ga * 512 + off;
            xp[j] = x16 + (size_t)ga * 128 + off;
            wtp[j] = nullptr;
        } else {
            wtp[j] = Wt + (size_t)(row - 64) * 640 + off;
            ybp[j] = nullptr;
            xp[j] = nullptr;
        }
    }

#define STAGE(bufbase, k0)                                                    \
    {                                                                         \
        _Pragma("unroll")                                                     \
        for (int j = 0; j < 3; j++) {                                         \
            const u16* s = wtp[j] ? (wtp[j] + (k0))                           \
                                  : ((k0) < 512 ? ybp[j] + (k0)               \
                                                : xp[j] + ((k0) - 512));      \
            gload16(s, LDS + (bufbase) + ldsoff[j]);                          \
        }                                                                     \
    }

    STAGE(0, 0);
    __syncthreads();
    int cur = 0;
    for (int t = 0; t < 20; t++) {
        if (t < 19) STAGE((cur ^ 1) * 12288, (t + 1) * 32);
        const char* Ab = LDS + cur * 12288;
        const char* Bb = Ab + 4096;
        s16x8 a[2], b[4];
#pragma unroll
        for (int m = 0; m < 2; m++) {
            const int row = wr * 32 + m * 16 + (lane & 15);
            a[m] = *(const s16x8*)(Ab + row * 64 +
                                   (((lane >> 4) ^ ((row >> 1) & 3)) << 4));
        }
#pragma unroll
        for (int n = 0; n < 4; n++) {
            const int col = wc * 64 + n * 16 + (lane & 15);
            b[n] = *(const s16x8*)(Bb + col * 64 +
                                   (((lane >> 4) ^ ((col >> 1) & 3)) << 4));
        }
#pragma unroll
        for (int m = 0; m < 2; m++)
#pragma unroll
            for (int n = 0; n < 4; n++)
                acc[m][n] = __builtin_amdgcn_mfma_f32_16x16x32_bf16(a[m], b[n],
                                                                    acc[m][n], 0, 0, 0);
        __syncthreads();   // waits next tile's loads (vmcnt) + LDS reads done
        cur ^= 1;
    }
#undef STAGE

    // epilogue: D frag col=lane&15, row=(lane>>4)*4+e. Fused BN stats.
    float bv[4], cs[4] = {}, cq[4] = {};
#pragma unroll
    for (int n = 0; n < 4; n++) bv[n] = bias[wc * 64 + n * 16 + (lane & 15)];
#pragma unroll
    for (int m = 0; m < 2; m++) {
        const int rb = bm + wr * 32 + m * 16 + ((lane >> 4) << 2);
#pragma unroll
        for (int e = 0; e < 4; e++) {
            const int r = rb + e;
            if (r < Nn) {
                float* op = OUT + (size_t)r * 128 + wc * 64 + (lane & 15);
#pragma unroll
                for (int n = 0; n < 4; n++) {
                    float v = fmaxf(acc[m][n][e] + bv[n], 0.f);
                    op[n * 16] = v;
                    cs[n] += v;
                    cq[n] += v * v;
                }
            }
        }
    }
#pragma unroll
    for (int n = 0; n < 4; n++) {
        cs[n] += __shfl_xor(cs[n], 16);
        cs[n] += __shfl_xor(cs[n], 32);
        cq[n] += __shfl_xor(cq[n], 16);
        cq[n] += __shfl_xor(cq[n], 32);
    }
    // cross-wave (wr) pre-reduce in LDS -> one atomic set per block
    float* red = (float*)LDS;
    if (wr == 1 && lane < 16) {
#pragma unroll
        for (int n = 0; n < 4; n++) {
            const int col = wc * 64 + n * 16 + lane;
            red[col] = cs[n];
            red[128 + col] = cq[n];
        }
    }
    __syncthreads();
    if (wr == 0 && lane < 16) {
#pragma unroll
        for (int n = 0; n < 4; n++) {
            const int col = wc * 64 + n * 16 + lane;
            unsafeAtomicAdd(&stats[col], cs[n] + red[col]);
            unsafeAtomicAdd(&stats[128 + col], cq[n] + red[128 + col]);
        }
    }
}

// ---------------- BN normalize (+ optional bf16 emit for next layer) ---------
__global__ __launch_bounds__(256) void norm_k(const float* __restrict__ h,
                                              const float* __restrict__ stats,
                                              const float* __restrict__ gamma,
                                              const float* __restrict__ beta,
                                              float* __restrict__ out,
                                              u16* __restrict__ xb) {
    const float invN = 1.0f / (float)Nn;
    int total = Nn * 32;
    for (int i = blockIdx.x * blockDim.x + threadIdx.x; i < total;
         i += gridDim.x * blockDim.x) {
        int c = (i & 31) * 4;
        float4 v = ((const float4*)h)[i];
        float4 o;
        {
            float mu = stats[c + 0] * invN;
            float var = stats[Dd + c + 0] * invN - mu * mu;
            o.x = gamma[c + 0] * (v.x - mu) * rsqrtf(var + EPSc) + beta[c + 0];
        }
        {
            float mu = stats[c + 1] * invN;
            float var = stats[Dd + c + 1] * invN - mu * mu;
            o.y = gamma[c + 1] * (v.y - mu) * rsqrtf(var + EPSc) + beta[c + 1];
        }
        {
            float mu = stats[c + 2] * invN;
            float var = stats[Dd + c + 2] * invN - mu * mu;
            o.z = gamma[c + 2] * (v.z - mu) * rsqrtf(var + EPSc) + beta[c + 2];
        }
        {
            float mu = stats[c + 3] * invN;
            float var = stats[Dd + c + 3] * invN - mu * mu;
            o.w = gamma[c + 3] * (v.w - mu) * rsqrtf(var + EPSc) + beta[c + 3];
        }
        ((float4*)out)[i] = o;
        if (xb) ((ushort4*)xb)[i] = make_ushort4(f2bf(o.x), f2bf(o.y),
                                                 f2bf(o.z), f2bf(o.w));
    }
}

// ---------------- launch ----------------
extern "C" void kernel_launch(void* const* d_in, const int* in_sizes, int n_in,
                              void* d_out, int out_size, void* d_ws, size_t ws_size,
                              hipStream_t stream) {
    const float* feat = (const float*)d_in[0];
    const int* src = (const int*)d_in[1];
    const int* dst = (const int*)d_in[2];
    const int* et = (const int*)d_in[3];
    float* out = (float*)d_out;

    // workspace (~69.2 MB)
    char* p = (char*)d_ws;
    u16* yb16 = (u16*)p;   p += (size_t)Nn * 512 * 2;                    // 51.2 MB
    u16* x16 = (u16*)p;    p += (size_t)Nn * 128 * 2;                    // 12.8 MB
    u16* Wt = (u16*)p;     p += (size_t)128 * 640 * 2;                   // 160 KB
    int* rowp = (int*)p;   p += ((((size_t)(Nn + 1) * 4) + 15) & ~15ull);
    int2* se = (int2*)p;   p += (size_t)Ee * 8;                          // 4.8 MB
    float* stats = (float*)p;
    int* cursor = (int*)yb16;  // dead before agg_k writes yb16

    // ---- CSR once ----
    hipMemsetAsync(cursor, 0, (size_t)Nn * 4, stream);
    hist_k<<<(Ee + 255) / 256, 256, 0, stream>>>(dst, cursor);
    scan_k<<<1, 1024, 0, stream>>>(cursor, rowp);
    hipMemcpyAsync(cursor, rowp, (size_t)Nn * 4, hipMemcpyDeviceToDevice, stream);
    scatter_k<<<(Ee + 255) / 256, 256, 0, stream>>>(src, dst, et, cursor, se);
    conv_k<<<1024, 256, 0, stream>>>(feat, x16);

    const int gx = (Nn + 63) / 64;  // 782

    for (int l = 0; l < 2; l++) {
        const float* V = (const float*)d_in[4 + 6 * l + 0];
        const float* comb = (const float*)d_in[4 + 6 * l + 1];
        const float* loop = (const float*)d_in[4 + 6 * l + 2];
        const float* bias = (const float*)d_in[4 + 6 * l + 3];
        const float* gamma = (const float*)d_in[4 + 6 * l + 4];
        const float* beta = (const float*)d_in[4 + 6 * l + 5];

        wprep_k<<<(128 * 640 + 255) / 256, 256, 0, stream>>>(V, loop, Wt);
        agg_k<<<(Nn + 3) / 4, 256, 0, stream>>>(x16, se, rowp, comb, yb16);
        hipMemsetAsync(stats, 0, 2 * Dd * sizeof(float), stream);
        gemm_mfma_k<<<gx, 256, 0, stream>>>(yb16, x16, Wt, bias, out, stats);
        norm_k<<<2048, 256, 0, stream>>>(out, stats, gamma, beta, out,
                                         (l == 0) ? x16 : nullptr);
    }
}